// Round 4
// baseline (322.012 us; speedup 1.0000x reference)
//
#include <hip/hip_runtime.h>
#include <cstdint>

#define KNB 16
#define FDIM 64
#define HDIM 128
#define SA 130          // Act row stride in f16 units (65 dwords -> conflict-free)
#define SW 65           // WT row stride in dwords

typedef unsigned long long ull;
typedef _Float16 f16x8 __attribute__((ext_vector_type(8)));
typedef float    f32x16 __attribute__((ext_vector_type(16)));

__device__ __forceinline__ float selu_f(float x){
    const float a = 1.6732632423543772f, s = 1.0507009873554805f;
    return x > 0.f ? s * x : s * a * expm1f(x);
}

__device__ __forceinline__ unsigned int pack2(float a, float b){
    union { _Float16 h[2]; unsigned int u; } t;
    t.h[0] = (_Float16)a; t.h[1] = (_Float16)b;
    return t.u;
}

__device__ __forceinline__ f16x8 ldfrag(const unsigned int* p, unsigned int di){
    union { unsigned int u[4]; f16x8 v; } t;
    t.u[0] = p[di]; t.u[1] = p[di+1]; t.u[2] = p[di+2]; t.u[3] = p[di+3];
    return t.v;
}

// ---------------------------------------------------------------------------
// Kernel 0: weights -> transposed fp16 (WT[n][k] = W[k][n]).
// ---------------------------------------------------------------------------
__global__ __launch_bounds__(256) void conv_kernel(
    const float* __restrict__ We1, const float* __restrict__ We2,
    const float* __restrict__ Wc1, _Float16* __restrict__ WT)
{
    int id = blockIdx.x * 256 + threadIdx.x;     // 0..49151
    int m  = id >> 14;
    int r  = id & 16383;
    int nn = (r >> 7) & 127;
    int k  = r & 127;
    float v;
    if (m == 0)      v = We1[(k + 1) * 128 + nn];
    else if (m == 1) v = We2[k * 128 + nn];
    else             v = Wc1[k * 128 + nn];
    WT[m * 16384 + nn * 128 + k] = (_Float16)v;
}

// ---------------------------------------------------------------------------
// Kernel 1: exact KNN, one 256-thread block per point.
// Round-3 post-mortem: ull key[20] was never promoted to registers
// (VGPR_Count=32 regardless of launch bounds) -> scratch/AGPR traffic made
// the kernel issue-bound at 144us. This version uses 20 NAMED scalar floats
// (no alloca to demote) and an incremental per-wave min so non-owner waves
// do ~16 inst/round.
// ---------------------------------------------------------------------------
#define D_LIST(X) X(0) X(1) X(2) X(3) X(4) X(5) X(6) X(7) X(8) X(9) \
                  X(10) X(11) X(12) X(13) X(14) X(15) X(16) X(17) X(18) X(19)

__global__ __launch_bounds__(256, 4) void knn_kernel(
    const float* __restrict__ coords,
    const int* __restrict__ row_splits, int nseg, int n,
    int* __restrict__ nidx, float* __restrict__ ndist, int* __restrict__ idx0,
    float* __restrict__ out_nidx, float* __restrict__ out_d)
{
    const int i    = blockIdx.x;
    const int tid  = threadIdx.x;
    const int lane = tid & 63, wid = tid >> 6;

    int lo = 0, hi = n;
    for (int s = 0; s < nseg; ++s){
        int a = row_splits[s], b = row_splits[s+1];
        if (i >= a && i < b){ lo = a; hi = b; }
    }

    const float cx = coords[3*i], cy = coords[3*i+1], cz = coords[3*i+2];
    const float nrmi = __fadd_rn(__fadd_rn(__fmul_rn(cx,cx), __fmul_rn(cy,cy)), __fmul_rn(cz,cz));

    const int jbase = lo + tid;
    const unsigned int INFB = 0x7f800000u;

    // ---- 20 named candidate d2 registers ----
#define DECL_D(C) float d##C;
    D_LIST(DECL_D)
#undef DECL_D

    ull m = ~0ull;
#define COMP_D(C) { \
        int j = jbase + (C)*256; \
        float dv = __uint_as_float(INFB); \
        if (j < hi){ \
            const float* cp = coords + 3*j; \
            float x = cp[0], y = cp[1], z = cp[2]; \
            float nrmj = __fadd_rn(__fadd_rn(__fmul_rn(x,x), __fmul_rn(y,y)), __fmul_rn(z,z)); \
            float dot  = __fadd_rn(__fadd_rn(__fmul_rn(cx,x), __fmul_rn(cy,y)), __fmul_rn(cz,z)); \
            float d2 = __fsub_rn(__fadd_rn(nrmi, nrmj), __fmul_rn(2.0f, dot)); \
            dv = fmaxf(d2, 0.0f); \
        } \
        d##C = dv; \
        ull kk = (((ull)__float_as_uint(dv)) << 32) | (unsigned int)(jbase + (C)*256); \
        m = kk < m ? kk : m; \
    }
    D_LIST(COMP_D)
#undef COMP_D

    __shared__ ull wavemin[2][4];

    // initial wave min -> parity 0
    {
        ull wm = m;
        #pragma unroll
        for (int off = 32; off > 0; off >>= 1){
            ull o = __shfl_down(wm, off, 64);
            wm = o < wm ? o : wm;
        }
        if (lane == 0) wavemin[0][wid] = wm;
    }
    __syncthreads();

    for (int r = 0; r < KNB + 1; ++r){
        const ull* wp = wavemin[r & 1];
        ull b0 = wp[0], b1 = wp[1], b2 = wp[2], b3 = wp[3];
        ull b  = b0 < b1 ? b0 : b1;
        ull t  = b2 < b3 ? b2 : b3;
        b = b < t ? b : t;

        bool ownlane = (m == b);
        if (ownlane){
            int   j  = (int)(b & 0xffffffffull);
            float dv = __uint_as_float((unsigned int)(b >> 32));
            if (r == 0){
                idx0[i] = j;
            } else {
                int rr = r - 1;
                nidx[i*KNB + rr]     = j;
                ndist[i*KNB + rr]    = dv;
                out_nidx[i*KNB + rr] = (float)j;
                out_d[i*KNB + rr]    = dv;
            }
            // kill matched entry + recompute local min
            m = ~0ull;
#define KILL_MIN(C) { \
                ull kk = (((ull)__float_as_uint(d##C)) << 32) | (unsigned int)(jbase + (C)*256); \
                if (kk == b) d##C = __uint_as_float(INFB); \
                kk = (((ull)__float_as_uint(d##C)) << 32) | (unsigned int)(jbase + (C)*256); \
                m = kk < m ? kk : m; \
            }
            D_LIST(KILL_MIN)
#undef KILL_MIN
        }

        // only the owner wave re-reduces; every wave forwards its min to the
        // next parity (lane 0)
        if (__any((int)ownlane)){
            ull wm = m;
            #pragma unroll
            for (int off = 32; off > 0; off >>= 1){
                ull o = __shfl_down(wm, off, 64);
                wm = o < wm ? o : wm;
            }
            if (lane == 0) wavemin[(r+1) & 1][wid] = wm;
        } else {
            if (lane == 0) wavemin[(r+1) & 1][wid] = wp[wid];
        }
        __syncthreads();
    }
}

// ---------------------------------------------------------------------------
// Kernel 2: 4 nodes (64 edges) per 256-thread block. (unchanged this round)
// ---------------------------------------------------------------------------
__global__ __launch_bounds__(256, 3) void egcn_node_kernel(
    const float* __restrict__ h, const float* __restrict__ coords,
    const int* __restrict__ nidx, const float* __restrict__ ndist,
    const int* __restrict__ idx0, const _Float16* __restrict__ WTg,
    const float* __restrict__ W_e1, const float* __restrict__ b_e1,
    const float* __restrict__ b_e2, const float* __restrict__ b_c1,
    const float* __restrict__ W_c2, const float* __restrict__ b_c2,
    const float* __restrict__ W_n1, const float* __restrict__ b_n1,
    const float* __restrict__ W_n2, const float* __restrict__ b_n2,
    float* __restrict__ out, float* __restrict__ out_coords, int n)
{
    __shared__ _Float16 Act[64 * SA];                       // 16640 B
    __shared__ union {
        unsigned int wt[128 * SW];                          // 33280 B
        struct { float part[2][4][128]; float an[4][128]; } p2;
    } U;
    __shared__ float agg[4][HDIM];
    __shared__ float dls[64];
    __shared__ int   nb[64];
    __shared__ int   j0s[4];
    __shared__ float wedge[64];
    __shared__ float wedgep[2][64];

    const int g0  = blockIdx.x * 4;
    const int tid = threadIdx.x;
    const int lane = tid & 63, wid = tid >> 6;
    const int ln31 = lane & 31, grp = lane >> 5;
    const int rt  = wid & 1;
    const int ct0 = (wid >> 1) * 2;

    if (tid < 64){
        int e = min(g0*KNB + tid, n*KNB - 1);
        nb[tid]  = nidx[e];
        dls[tid] = ndist[e];
    }
    if (tid < 4) j0s[tid] = idx0[min(g0 + tid, n - 1)];
    __syncthreads();

    unsigned int* actd = (unsigned int*)Act;

    {
        int r = tid >> 2, q = tid & 3, f0 = q * 16;
        const float* hs = h + (size_t)j0s[r >> 4] * FDIM + f0;
        const float* hn = h + (size_t)nb[r] * FDIM + f0;
        unsigned int ds = (unsigned int)(r * SA + f0) >> 1;
        unsigned int dn = (unsigned int)(r * SA + FDIM + f0) >> 1;
        #pragma unroll
        for (int j = 0; j < 8; ++j){
            actd[ds + j] = pack2(hs[2*j], hs[2*j+1]);
            actd[dn + j] = pack2(hn[2*j], hn[2*j+1]);
        }
    }
    {
        int nr = tid >> 1, kh = (tid & 1) * 64;
        const uint4* src = (const uint4*)(WTg + nr * 128 + kh);
        unsigned int* dst = U.wt + nr * SW + (tid & 1) * 32;
        #pragma unroll
        for (int j = 0; j < 8; ++j){
            uint4 x = src[j];
            dst[j*4+0]=x.x; dst[j*4+1]=x.y; dst[j*4+2]=x.z; dst[j*4+3]=x.w;
        }
    }
    __syncthreads();

    const unsigned int aBase  = (unsigned int)(rt*32 + ln31) * SW + grp*4;
    const unsigned int bBase0 = (unsigned int)(ct0*32 + ln31) * SW + grp*4;
    const unsigned int bBase1 = (unsigned int)((ct0+1)*32 + ln31) * SW + grp*4;

    auto gemm2 = [&](f32x16& A0, f32x16& A1){
        #pragma unroll
        for (int ks = 0; ks < 8; ++ks){
            const unsigned int off = ks * 8;
            f16x8 af  = ldfrag(actd, aBase + off);
            f16x8 bf0 = ldfrag(U.wt, bBase0 + off);
            f16x8 bf1 = ldfrag(U.wt, bBase1 + off);
            A0 = __builtin_amdgcn_mfma_f32_32x32x16_f16(af, bf0, A0, 0, 0, 0);
            A1 = __builtin_amdgcn_mfma_f32_32x32x16_f16(af, bf1, A1, 0, 0, 0);
        }
    };
    auto stage_wt = [&](const _Float16* Wg){
        int nr = tid >> 1, kh = (tid & 1) * 64;
        const uint4* src = (const uint4*)(Wg + nr * 128 + kh);
        unsigned int* dst = U.wt + nr * SW + (tid & 1) * 32;
        #pragma unroll
        for (int j = 0; j < 8; ++j){
            uint4 x = src[j];
            dst[j*4+0]=x.x; dst[j*4+1]=x.y; dst[j*4+2]=x.z; dst[j*4+3]=x.w;
        }
    };

    // ================= layer e1 (129 -> 128) =================
    {
        float w0a = W_e1[ct0*32 + ln31], w0b = W_e1[(ct0+1)*32 + ln31];
        float bza = b_e1[ct0*32 + ln31], bzb = b_e1[(ct0+1)*32 + ln31];
        f32x16 a0, a1;
        #pragma unroll
        for (int reg = 0; reg < 16; ++reg){
            int row32 = (reg&3) + 8*(reg>>2) + 4*grp;
            float dv = dls[rt*32 + row32];
            a0[reg] = fmaf(dv, w0a, bza);
            a1[reg] = fmaf(dv, w0b, bzb);
        }
        gemm2(a0, a1);
        __syncthreads();
        #pragma unroll
        for (int reg = 0; reg < 16; ++reg){
            int row = rt*32 + (reg&3) + 8*(reg>>2) + 4*grp;
            Act[row*SA + ct0*32 + ln31]     = (_Float16)selu_f(a0[reg]);
            Act[row*SA + (ct0+1)*32 + ln31] = (_Float16)selu_f(a1[reg]);
        }
        stage_wt(WTg + 16384);
        __syncthreads();
    }

    // ================= layer e2 (128 -> 128), e_sum fused =================
    {
        float bza = b_e2[ct0*32 + ln31], bzb = b_e2[(ct0+1)*32 + ln31];
        f32x16 a0, a1;
        #pragma unroll
        for (int reg = 0; reg < 16; ++reg){ a0[reg] = bza; a1[reg] = bzb; }
        gemm2(a0, a1);
        __syncthreads();
        float ev0[16], ev1[16];
        float slo0 = 0.f, shi0 = 0.f, slo1 = 0.f, shi1 = 0.f;
        #pragma unroll
        for (int reg = 0; reg < 16; ++reg){
            ev0[reg] = selu_f(a0[reg]);
            ev1[reg] = selu_f(a1[reg]);
            if (reg < 8){ slo0 += ev0[reg]; slo1 += ev1[reg]; }
            else        { shi0 += ev0[reg]; shi1 += ev1[reg]; }
        }
        slo0 += __shfl_xor(slo0, 32, 64);
        shi0 += __shfl_xor(shi0, 32, 64);
        slo1 += __shfl_xor(slo1, 32, 64);
        shi1 += __shfl_xor(shi1, 32, 64);
        if (grp == 0){
            agg[rt*2+0][ct0*32 + ln31]     = slo0;
            agg[rt*2+1][ct0*32 + ln31]     = shi0;
            agg[rt*2+0][(ct0+1)*32 + ln31] = slo1;
            agg[rt*2+1][(ct0+1)*32 + ln31] = shi1;
        }
        #pragma unroll
        for (int reg = 0; reg < 16; ++reg){
            int row = rt*32 + (reg&3) + 8*(reg>>2) + 4*grp;
            Act[row*SA + ct0*32 + ln31]     = (_Float16)ev0[reg];
            Act[row*SA + (ct0+1)*32 + ln31] = (_Float16)ev1[reg];
        }
        stage_wt(WTg + 2*16384);
        __syncthreads();
    }

    // ================= layer c1 (128 -> 128) + c2 fused =================
    {
        float bza = b_c1[ct0*32 + ln31], bzb = b_c1[(ct0+1)*32 + ln31];
        f32x16 a0, a1;
        #pragma unroll
        for (int reg = 0; reg < 16; ++reg){ a0[reg] = bza; a1[reg] = bzb; }
        gemm2(a0, a1);
        __syncthreads();
        float wca = W_c2[ct0*32 + ln31], wcb = W_c2[(ct0+1)*32 + ln31];
        float p[16];
        #pragma unroll
        for (int reg = 0; reg < 16; ++reg)
            p[reg] = selu_f(a0[reg]) * wca + selu_f(a1[reg]) * wcb;
        #pragma unroll
        for (int msk = 16; msk > 0; msk >>= 1){
            #pragma unroll
            for (int reg = 0; reg < 16; ++reg)
                p[reg] += __shfl_xor(p[reg], msk, 64);
        }
        if (ln31 == 0){
            #pragma unroll
            for (int reg = 0; reg < 16; ++reg){
                int row = rt*32 + (reg&3) + 8*(reg>>2) + 4*grp;
                wedgep[wid>>1][row] = p[reg];
            }
        }
        __syncthreads();
    }

    // ================= epilogue: wedge, coords, node MLP =================
    if (tid < 64) wedge[tid] = b_c2[0] + wedgep[0][tid] + wedgep[1][tid];
    __syncthreads();

    if (tid < 12){
        int nd = tid / 3, c = tid - nd*3;
        int gi = min(g0 + nd, n - 1);
        float ci = coords[3*gi + c];
        float s = 0.f;
        #pragma unroll
        for (int k = 0; k < KNB; ++k){
            int e = nd*KNB + k;
            s += (ci - coords[3*nb[e] + c]) * wedge[e];
        }
        if (g0 + nd < n) out_coords[3*gi + c] = ci + s * (1.0f/KNB);
    }

    int jds[4];
    #pragma unroll
    for (int nd = 0; nd < 4; ++nd) jds[nd] = __builtin_amdgcn_readfirstlane(j0s[nd]);

    {
        int o = tid & 127, half = tid >> 7;
        float a[4] = {0.f, 0.f, 0.f, 0.f};
        if (half == 0){
            for (int in = 0; in < 96; ++in){
                float w = W_n1[in*HDIM + o];
                #pragma unroll
                for (int nd = 0; nd < 4; ++nd) a[nd] = fmaf(agg[nd][in], w, a[nd]);
            }
        } else {
            for (int in = 96; in < 128; ++in){
                float w = W_n1[in*HDIM + o];
                #pragma unroll
                for (int nd = 0; nd < 4; ++nd) a[nd] = fmaf(agg[nd][in], w, a[nd]);
            }
            for (int f = 0; f < 64; ++f){
                float w = W_n1[(128 + f)*HDIM + o];
                #pragma unroll
                for (int nd = 0; nd < 4; ++nd)
                    a[nd] = fmaf(h[(size_t)jds[nd]*FDIM + f], w, a[nd]);
            }
        }
        #pragma unroll
        for (int nd = 0; nd < 4; ++nd) U.p2.part[half][nd][o] = a[nd];
        __syncthreads();
        for (int s = tid; s < 512; s += 256){
            int nd = s >> 7, o2 = s & 127;
            U.p2.an[nd][o2] = selu_f(U.p2.part[0][nd][o2] + U.p2.part[1][nd][o2] + b_n1[o2]);
        }
        __syncthreads();
        float b[4] = {0.f, 0.f, 0.f, 0.f};
        int lo2 = half * 64;
        for (int in = lo2; in < lo2 + 64; ++in){
            float w = W_n2[in*HDIM + o];
            #pragma unroll
            for (int nd = 0; nd < 4; ++nd) b[nd] = fmaf(U.p2.an[nd][in], w, b[nd]);
        }
        __syncthreads();
        #pragma unroll
        for (int nd = 0; nd < 4; ++nd) U.p2.part[half][nd][o] = b[nd];
        __syncthreads();
        for (int s = tid; s < 512; s += 256){
            int nd = s >> 7, o2 = s & 127;
            if (g0 + nd < n)
                out[(size_t)(g0 + nd)*HDIM + o2] =
                    U.p2.part[0][nd][o2] + U.p2.part[1][nd][o2] + b_n2[o2];
        }
    }
}

extern "C" void kernel_launch(void* const* d_in, const int* in_sizes, int n_in,
                              void* d_out, int out_size, void* d_ws, size_t ws_size,
                              hipStream_t stream)
{
    const float* h          = (const float*)d_in[0];
    const float* coords     = (const float*)d_in[1];
    const int*   row_splits = (const int*)  d_in[2];
    const float* W_e1 = (const float*)d_in[3];
    const float* b_e1 = (const float*)d_in[4];
    const float* W_e2 = (const float*)d_in[5];
    const float* b_e2 = (const float*)d_in[6];
    const float* W_c1 = (const float*)d_in[7];
    const float* b_c1 = (const float*)d_in[8];
    const float* W_c2 = (const float*)d_in[9];
    const float* b_c2 = (const float*)d_in[10];
    const float* W_n1 = (const float*)d_in[11];
    const float* b_n1 = (const float*)d_in[12];
    const float* W_n2 = (const float*)d_in[13];
    const float* b_n2 = (const float*)d_in[14];

    const int n    = in_sizes[0] / FDIM;
    const int nseg = in_sizes[2] - 1;

    float* out        = (float*)d_out;
    float* out_coords = out + (size_t)n * HDIM;
    float* out_nidx   = out_coords + (size_t)n * 3;
    float* out_d      = out_nidx + (size_t)n * KNB;

    int*       nidx_i = (int*)d_ws;
    float*     ndist  = (float*)(nidx_i + (size_t)n * KNB);
    int*       idx0   = (int*)(ndist + (size_t)n * KNB);
    _Float16*  WT     = (_Float16*)(idx0 + (size_t)n);   // 3 x 128 x 128 fp16

    conv_kernel<<<192, 256, 0, stream>>>(W_e1, W_e2, W_c1, WT);

    knn_kernel<<<n, 256, 0, stream>>>(coords, row_splits, nseg, n,
                                      nidx_i, ndist, idx0, out_nidx, out_d);

    egcn_node_kernel<<<(n + 3) / 4, 256, 0, stream>>>(
        h, coords, nidx_i, ndist, idx0, WT,
        W_e1, b_e1, b_e2, b_c1, W_c2, b_c2,
        W_n1, b_n1, W_n2, b_n2,
        out, out_coords, n);
}

// Round 5
// 302.463 us; speedup vs baseline: 1.0646x; 1.0646x over previous
//
#include <hip/hip_runtime.h>
#include <cstdint>

#define KNB 16
#define FDIM 64
#define HDIM 128
#define SA 130          // Act row stride in f16 units (65 dwords -> conflict-free)
#define SW 65           // WT row stride in dwords
#define CMAX 20         // candidates per thread (covers segments up to 5120)

typedef unsigned long long ull;
typedef _Float16 f16x8 __attribute__((ext_vector_type(8)));
typedef float    f32x16 __attribute__((ext_vector_type(16)));

__device__ __forceinline__ float selu_f(float x){
    const float a = 1.6732632423543772f, s = 1.0507009873554805f;
    return x > 0.f ? s * x : s * a * expm1f(x);
}

__device__ __forceinline__ unsigned int pack2(float a, float b){
    union { _Float16 h[2]; unsigned int u; } t;
    t.h[0] = (_Float16)a; t.h[1] = (_Float16)b;
    return t.u;
}

__device__ __forceinline__ f16x8 ldfrag(const unsigned int* p, unsigned int di){
    union { unsigned int u[4]; f16x8 v; } t;
    t.u[0] = p[di]; t.u[1] = p[di+1]; t.u[2] = p[di+2]; t.u[3] = p[di+3];
    return t.v;
}

// ---------------------------------------------------------------------------
// Kernel 0: weights -> transposed fp16 (WT[n][k] = W[k][n]).
// ---------------------------------------------------------------------------
__global__ __launch_bounds__(256) void conv_kernel(
    const float* __restrict__ We1, const float* __restrict__ We2,
    const float* __restrict__ Wc1, _Float16* __restrict__ WT)
{
    int id = blockIdx.x * 256 + threadIdx.x;     // 0..49151
    int m  = id >> 14;
    int r  = id & 16383;
    int nn = (r >> 7) & 127;
    int k  = r & 127;
    float v;
    if (m == 0)      v = We1[(k + 1) * 128 + nn];
    else if (m == 1) v = We2[k * 128 + nn];
    else             v = Wc1[k * 128 + nn];
    WT[m * 16384 + nn * 128 + k] = (_Float16)v;
}

// ---------------------------------------------------------------------------
// Kernel 1: exact KNN, one 256-thread block per point.
// R4 post-mortem: owner-wave 20-key rescan (~240 exec-masked u64 ops) was
// ~2/3 of all round instructions. This version keeps a per-lane TOP-3 key
// cache (named regs, branchless insert) so ownership is a 3-reg shift;
// d2 values are backed up in LDS and rescanned only on a lane's 4th
// ownership (P ~ 1e-4 per block), filtered by key > b (extraction order is
// globally increasing, so keys <= b are provably extracted).
// ---------------------------------------------------------------------------
__global__ __launch_bounds__(256, 4) void knn_kernel(
    const float* __restrict__ coords,
    const int* __restrict__ row_splits, int nseg, int n,
    int* __restrict__ nidx, float* __restrict__ ndist, int* __restrict__ idx0,
    float* __restrict__ out_nidx, float* __restrict__ out_d)
{
    const int i    = blockIdx.x;
    const int tid  = threadIdx.x;
    const int lane = tid & 63, wid = tid >> 6;

    int lo = 0, hi = n;
    for (int s = 0; s < nseg; ++s){
        int a = row_splits[s], b = row_splits[s+1];
        if (i >= a && i < b){ lo = a; hi = b; }
    }

    const float cx = coords[3*i], cy = coords[3*i+1], cz = coords[3*i+2];
    const float nrmi = __fadd_rn(__fadd_rn(__fmul_rn(cx,cx), __fmul_rn(cy,cy)), __fmul_rn(cz,cz));

    const int jbase = lo + tid;
    const float FINF = __uint_as_float(0x7f800000u);

    __shared__ float d2s[CMAX][256];      // 20 KB backup of per-lane d2
    __shared__ ull   wavemin[2][4];

    // ---- pass 1: distances + LDS backup + per-lane top-3 ----
    ull m1 = ~0ull, m2 = ~0ull, m3 = ~0ull;
    #pragma unroll
    for (int c = 0; c < CMAX; ++c){
        int j = jbase + c*256;
        float dv = FINF;
        if (j < hi){
            const float* cp = coords + 3*j;
            float x = cp[0], y = cp[1], z = cp[2];
            float nrmj = __fadd_rn(__fadd_rn(__fmul_rn(x,x), __fmul_rn(y,y)), __fmul_rn(z,z));
            float dot  = __fadd_rn(__fadd_rn(__fmul_rn(cx,x), __fmul_rn(cy,y)), __fmul_rn(cz,z));
            float d2 = __fsub_rn(__fadd_rn(nrmi, nrmj), __fmul_rn(2.0f, dot));
            dv = fmaxf(d2, 0.0f);
        }
        d2s[c][tid] = dv;
        ull kk = (((ull)__float_as_uint(dv)) << 32) | (unsigned int)(j);
        // branchless top-3 insert
        ull n1 = kk < m1 ? kk : m1;
        ull t1 = kk < m1 ? m1 : kk;
        ull n2 = t1 < m2 ? t1 : m2;
        ull t2 = t1 < m2 ? m2 : t1;
        ull n3 = t2 < m3 ? t2 : m3;
        m1 = n1; m2 = n2; m3 = n3;
    }
    int vcnt = 3;

    // initial wave min -> parity 0
    {
        ull wm = m1;
        #pragma unroll
        for (int off = 32; off > 0; off >>= 1){
            ull o = __shfl_down(wm, off, 64);
            wm = o < wm ? o : wm;
        }
        if (lane == 0) wavemin[0][wid] = wm;
    }
    __syncthreads();

    for (int r = 0; r < KNB + 1; ++r){
        const ull* wp = wavemin[r & 1];
        ull b0 = wp[0], b1 = wp[1], b2 = wp[2], b3 = wp[3];
        ull b  = b0 < b1 ? b0 : b1;
        ull t  = b2 < b3 ? b2 : b3;
        b = b < t ? b : t;

        bool ownlane = (m1 == b);
        if (ownlane){
            int   j  = (int)(b & 0xffffffffull);
            float dv = __uint_as_float((unsigned int)(b >> 32));
            if (r == 0){
                idx0[i] = j;
            } else {
                int rr = r - 1;
                nidx[i*KNB + rr]     = j;
                ndist[i*KNB + rr]    = dv;
                out_nidx[i*KNB + rr] = (float)j;
                out_d[i*KNB + rr]    = dv;
            }
            m1 = m2; m2 = m3; m3 = ~0ull;
            if (--vcnt == 0){
                // rare refill: 3 smallest local keys strictly greater than b
                m1 = m2 = m3 = ~0ull;
                #pragma unroll
                for (int c = 0; c < CMAX; ++c){
                    float dv2 = d2s[c][tid];
                    ull kk = (((ull)__float_as_uint(dv2)) << 32) | (unsigned int)(jbase + c*256);
                    kk = kk > b ? kk : ~0ull;
                    ull n1 = kk < m1 ? kk : m1;
                    ull t1 = kk < m1 ? m1 : kk;
                    ull n2 = t1 < m2 ? t1 : m2;
                    ull t2 = t1 < m2 ? m2 : t1;
                    ull n3 = t2 < m3 ? t2 : m3;
                    m1 = n1; m2 = n2; m3 = n3;
                }
                vcnt = 3;
            }
        }

        if (__any((int)ownlane)){
            ull wm = m1;
            #pragma unroll
            for (int off = 32; off > 0; off >>= 1){
                ull o = __shfl_down(wm, off, 64);
                wm = o < wm ? o : wm;
            }
            if (lane == 0) wavemin[(r+1) & 1][wid] = wm;
        } else {
            if (lane == 0) wavemin[(r+1) & 1][wid] = wp[wid];
        }
        __syncthreads();
    }
}

// ---------------------------------------------------------------------------
// Kernel 2: 4 nodes (64 edges) per 256-thread block. (unchanged this round)
// ---------------------------------------------------------------------------
__global__ __launch_bounds__(256, 3) void egcn_node_kernel(
    const float* __restrict__ h, const float* __restrict__ coords,
    const int* __restrict__ nidx, const float* __restrict__ ndist,
    const int* __restrict__ idx0, const _Float16* __restrict__ WTg,
    const float* __restrict__ W_e1, const float* __restrict__ b_e1,
    const float* __restrict__ b_e2, const float* __restrict__ b_c1,
    const float* __restrict__ W_c2, const float* __restrict__ b_c2,
    const float* __restrict__ W_n1, const float* __restrict__ b_n1,
    const float* __restrict__ W_n2, const float* __restrict__ b_n2,
    float* __restrict__ out, float* __restrict__ out_coords, int n)
{
    __shared__ _Float16 Act[64 * SA];                       // 16640 B
    __shared__ union {
        unsigned int wt[128 * SW];                          // 33280 B
        struct { float part[2][4][128]; float an[4][128]; } p2;
    } U;
    __shared__ float agg[4][HDIM];
    __shared__ float dls[64];
    __shared__ int   nb[64];
    __shared__ int   j0s[4];
    __shared__ float wedge[64];
    __shared__ float wedgep[2][64];

    const int g0  = blockIdx.x * 4;
    const int tid = threadIdx.x;
    const int lane = tid & 63, wid = tid >> 6;
    const int ln31 = lane & 31, grp = lane >> 5;
    const int rt  = wid & 1;
    const int ct0 = (wid >> 1) * 2;

    if (tid < 64){
        int e = min(g0*KNB + tid, n*KNB - 1);
        nb[tid]  = nidx[e];
        dls[tid] = ndist[e];
    }
    if (tid < 4) j0s[tid] = idx0[min(g0 + tid, n - 1)];
    __syncthreads();

    unsigned int* actd = (unsigned int*)Act;

    {
        int r = tid >> 2, q = tid & 3, f0 = q * 16;
        const float* hs = h + (size_t)j0s[r >> 4] * FDIM + f0;
        const float* hn = h + (size_t)nb[r] * FDIM + f0;
        unsigned int ds = (unsigned int)(r * SA + f0) >> 1;
        unsigned int dn = (unsigned int)(r * SA + FDIM + f0) >> 1;
        #pragma unroll
        for (int j = 0; j < 8; ++j){
            actd[ds + j] = pack2(hs[2*j], hs[2*j+1]);
            actd[dn + j] = pack2(hn[2*j], hn[2*j+1]);
        }
    }
    {
        int nr = tid >> 1, kh = (tid & 1) * 64;
        const uint4* src = (const uint4*)(WTg + nr * 128 + kh);
        unsigned int* dst = U.wt + nr * SW + (tid & 1) * 32;
        #pragma unroll
        for (int j = 0; j < 8; ++j){
            uint4 x = src[j];
            dst[j*4+0]=x.x; dst[j*4+1]=x.y; dst[j*4+2]=x.z; dst[j*4+3]=x.w;
        }
    }
    __syncthreads();

    const unsigned int aBase  = (unsigned int)(rt*32 + ln31) * SW + grp*4;
    const unsigned int bBase0 = (unsigned int)(ct0*32 + ln31) * SW + grp*4;
    const unsigned int bBase1 = (unsigned int)((ct0+1)*32 + ln31) * SW + grp*4;

    auto gemm2 = [&](f32x16& A0, f32x16& A1){
        #pragma unroll
        for (int ks = 0; ks < 8; ++ks){
            const unsigned int off = ks * 8;
            f16x8 af  = ldfrag(actd, aBase + off);
            f16x8 bf0 = ldfrag(U.wt, bBase0 + off);
            f16x8 bf1 = ldfrag(U.wt, bBase1 + off);
            A0 = __builtin_amdgcn_mfma_f32_32x32x16_f16(af, bf0, A0, 0, 0, 0);
            A1 = __builtin_amdgcn_mfma_f32_32x32x16_f16(af, bf1, A1, 0, 0, 0);
        }
    };
    auto stage_wt = [&](const _Float16* Wg){
        int nr = tid >> 1, kh = (tid & 1) * 64;
        const uint4* src = (const uint4*)(Wg + nr * 128 + kh);
        unsigned int* dst = U.wt + nr * SW + (tid & 1) * 32;
        #pragma unroll
        for (int j = 0; j < 8; ++j){
            uint4 x = src[j];
            dst[j*4+0]=x.x; dst[j*4+1]=x.y; dst[j*4+2]=x.z; dst[j*4+3]=x.w;
        }
    };

    // ================= layer e1 (129 -> 128) =================
    {
        float w0a = W_e1[ct0*32 + ln31], w0b = W_e1[(ct0+1)*32 + ln31];
        float bza = b_e1[ct0*32 + ln31], bzb = b_e1[(ct0+1)*32 + ln31];
        f32x16 a0, a1;
        #pragma unroll
        for (int reg = 0; reg < 16; ++reg){
            int row32 = (reg&3) + 8*(reg>>2) + 4*grp;
            float dv = dls[rt*32 + row32];
            a0[reg] = fmaf(dv, w0a, bza);
            a1[reg] = fmaf(dv, w0b, bzb);
        }
        gemm2(a0, a1);
        __syncthreads();
        #pragma unroll
        for (int reg = 0; reg < 16; ++reg){
            int row = rt*32 + (reg&3) + 8*(reg>>2) + 4*grp;
            Act[row*SA + ct0*32 + ln31]     = (_Float16)selu_f(a0[reg]);
            Act[row*SA + (ct0+1)*32 + ln31] = (_Float16)selu_f(a1[reg]);
        }
        stage_wt(WTg + 16384);
        __syncthreads();
    }

    // ================= layer e2 (128 -> 128), e_sum fused =================
    {
        float bza = b_e2[ct0*32 + ln31], bzb = b_e2[(ct0+1)*32 + ln31];
        f32x16 a0, a1;
        #pragma unroll
        for (int reg = 0; reg < 16; ++reg){ a0[reg] = bza; a1[reg] = bzb; }
        gemm2(a0, a1);
        __syncthreads();
        float ev0[16], ev1[16];
        float slo0 = 0.f, shi0 = 0.f, slo1 = 0.f, shi1 = 0.f;
        #pragma unroll
        for (int reg = 0; reg < 16; ++reg){
            ev0[reg] = selu_f(a0[reg]);
            ev1[reg] = selu_f(a1[reg]);
            if (reg < 8){ slo0 += ev0[reg]; slo1 += ev1[reg]; }
            else        { shi0 += ev0[reg]; shi1 += ev1[reg]; }
        }
        slo0 += __shfl_xor(slo0, 32, 64);
        shi0 += __shfl_xor(shi0, 32, 64);
        slo1 += __shfl_xor(slo1, 32, 64);
        shi1 += __shfl_xor(shi1, 32, 64);
        if (grp == 0){
            agg[rt*2+0][ct0*32 + ln31]     = slo0;
            agg[rt*2+1][ct0*32 + ln31]     = shi0;
            agg[rt*2+0][(ct0+1)*32 + ln31] = slo1;
            agg[rt*2+1][(ct0+1)*32 + ln31] = shi1;
        }
        #pragma unroll
        for (int reg = 0; reg < 16; ++reg){
            int row = rt*32 + (reg&3) + 8*(reg>>2) + 4*grp;
            Act[row*SA + ct0*32 + ln31]     = (_Float16)ev0[reg];
            Act[row*SA + (ct0+1)*32 + ln31] = (_Float16)ev1[reg];
        }
        stage_wt(WTg + 2*16384);
        __syncthreads();
    }

    // ================= layer c1 (128 -> 128) + c2 fused =================
    {
        float bza = b_c1[ct0*32 + ln31], bzb = b_c1[(ct0+1)*32 + ln31];
        f32x16 a0, a1;
        #pragma unroll
        for (int reg = 0; reg < 16; ++reg){ a0[reg] = bza; a1[reg] = bzb; }
        gemm2(a0, a1);
        __syncthreads();
        float wca = W_c2[ct0*32 + ln31], wcb = W_c2[(ct0+1)*32 + ln31];
        float p[16];
        #pragma unroll
        for (int reg = 0; reg < 16; ++reg)
            p[reg] = selu_f(a0[reg]) * wca + selu_f(a1[reg]) * wcb;
        #pragma unroll
        for (int msk = 16; msk > 0; msk >>= 1){
            #pragma unroll
            for (int reg = 0; reg < 16; ++reg)
                p[reg] += __shfl_xor(p[reg], msk, 64);
        }
        if (ln31 == 0){
            #pragma unroll
            for (int reg = 0; reg < 16; ++reg){
                int row = rt*32 + (reg&3) + 8*(reg>>2) + 4*grp;
                wedgep[wid>>1][row] = p[reg];
            }
        }
        __syncthreads();
    }

    // ================= epilogue: wedge, coords, node MLP =================
    if (tid < 64) wedge[tid] = b_c2[0] + wedgep[0][tid] + wedgep[1][tid];
    __syncthreads();

    if (tid < 12){
        int nd = tid / 3, c = tid - nd*3;
        int gi = min(g0 + nd, n - 1);
        float ci = coords[3*gi + c];
        float s = 0.f;
        #pragma unroll
        for (int k = 0; k < KNB; ++k){
            int e = nd*KNB + k;
            s += (ci - coords[3*nb[e] + c]) * wedge[e];
        }
        if (g0 + nd < n) out_coords[3*gi + c] = ci + s * (1.0f/KNB);
    }

    int jds[4];
    #pragma unroll
    for (int nd = 0; nd < 4; ++nd) jds[nd] = __builtin_amdgcn_readfirstlane(j0s[nd]);

    {
        int o = tid & 127, half = tid >> 7;
        float a[4] = {0.f, 0.f, 0.f, 0.f};
        if (half == 0){
            for (int in = 0; in < 96; ++in){
                float w = W_n1[in*HDIM + o];
                #pragma unroll
                for (int nd = 0; nd < 4; ++nd) a[nd] = fmaf(agg[nd][in], w, a[nd]);
            }
        } else {
            for (int in = 96; in < 128; ++in){
                float w = W_n1[in*HDIM + o];
                #pragma unroll
                for (int nd = 0; nd < 4; ++nd) a[nd] = fmaf(agg[nd][in], w, a[nd]);
            }
            for (int f = 0; f < 64; ++f){
                float w = W_n1[(128 + f)*HDIM + o];
                #pragma unroll
                for (int nd = 0; nd < 4; ++nd)
                    a[nd] = fmaf(h[(size_t)jds[nd]*FDIM + f], w, a[nd]);
            }
        }
        #pragma unroll
        for (int nd = 0; nd < 4; ++nd) U.p2.part[half][nd][o] = a[nd];
        __syncthreads();
        for (int s = tid; s < 512; s += 256){
            int nd = s >> 7, o2 = s & 127;
            U.p2.an[nd][o2] = selu_f(U.p2.part[0][nd][o2] + U.p2.part[1][nd][o2] + b_n1[o2]);
        }
        __syncthreads();
        float b[4] = {0.f, 0.f, 0.f, 0.f};
        int lo2 = half * 64;
        for (int in = lo2; in < lo2 + 64; ++in){
            float w = W_n2[in*HDIM + o];
            #pragma unroll
            for (int nd = 0; nd < 4; ++nd) b[nd] = fmaf(U.p2.an[nd][in], w, b[nd]);
        }
        __syncthreads();
        #pragma unroll
        for (int nd = 0; nd < 4; ++nd) U.p2.part[half][nd][o] = b[nd];
        __syncthreads();
        for (int s = tid; s < 512; s += 256){
            int nd = s >> 7, o2 = s & 127;
            if (g0 + nd < n)
                out[(size_t)(g0 + nd)*HDIM + o2] =
                    U.p2.part[0][nd][o2] + U.p2.part[1][nd][o2] + b_n2[o2];
        }
    }
}

extern "C" void kernel_launch(void* const* d_in, const int* in_sizes, int n_in,
                              void* d_out, int out_size, void* d_ws, size_t ws_size,
                              hipStream_t stream)
{
    const float* h          = (const float*)d_in[0];
    const float* coords     = (const float*)d_in[1];
    const int*   row_splits = (const int*)  d_in[2];
    const float* W_e1 = (const float*)d_in[3];
    const float* b_e1 = (const float*)d_in[4];
    const float* W_e2 = (const float*)d_in[5];
    const float* b_e2 = (const float*)d_in[6];
    const float* W_c1 = (const float*)d_in[7];
    const float* b_c1 = (const float*)d_in[8];
    const float* W_c2 = (const float*)d_in[9];
    const float* b_c2 = (const float*)d_in[10];
    const float* W_n1 = (const float*)d_in[11];
    const float* b_n1 = (const float*)d_in[12];
    const float* W_n2 = (const float*)d_in[13];
    const float* b_n2 = (const float*)d_in[14];

    const int n    = in_sizes[0] / FDIM;
    const int nseg = in_sizes[2] - 1;

    float* out        = (float*)d_out;
    float* out_coords = out + (size_t)n * HDIM;
    float* out_nidx   = out_coords + (size_t)n * 3;
    float* out_d      = out_nidx + (size_t)n * KNB;

    int*       nidx_i = (int*)d_ws;
    float*     ndist  = (float*)(nidx_i + (size_t)n * KNB);
    int*       idx0   = (int*)(ndist + (size_t)n * KNB);
    _Float16*  WT     = (_Float16*)(idx0 + (size_t)n);   // 3 x 128 x 128 fp16

    conv_kernel<<<192, 256, 0, stream>>>(W_e1, W_e2, W_c1, WT);

    knn_kernel<<<n, 256, 0, stream>>>(coords, row_splits, nseg, n,
                                      nidx_i, ndist, idx0, out_nidx, out_d);

    egcn_node_kernel<<<(n + 3) / 4, 256, 0, stream>>>(
        h, coords, nidx_i, ndist, idx0, WT,
        W_e1, b_e1, b_e2, b_c1, W_c2, b_c2,
        W_n1, b_n1, W_n2, b_n2,
        out, out_coords, n);
}